// Round 5
// baseline (230.613 us; speedup 1.0000x reference)
//
#include <hip/hip_runtime.h>
#include <math.h>

#define Hd 192
#define Wd 640
#define HWp (Hd * Wd)
#define NCLS 3
#define KTOP 50
#define NB 32
#define NPL (NB * NCLS)   // 96 planes
#define GPR 160           // 4-pixel groups per row (fallback scanner)
#define GPP (HWp / 4)     // 30720 groups per plane (fallback scanner)
#define SPR 40            // 16-px strips per row
#define SPP (Hd * SPR)    // 7680 strips per plane
#define SEGBLK 30         // scan blocks per plane (256 strips = 4096 px each)
#define SEGCAP 64         // candidate slots per scan block (E~20, 10 sigma)
#define CAP 2048          // per-plane candidate cap for ranking
#define RBK 256           // rank buckets
#define PI_F 3.14159265358979f

__device__ inline float fmax3(float a, float b, float c) {
  return fmaxf(fmaxf(a, b), c);
}

// ---------------------------------------------------------------------------
// Fallback 4-px-group peak scanner (exact radix rescan path only).
// ---------------------------------------------------------------------------
template <typename F>
__device__ inline void peaks_in_group(const float* __restrict__ p, int g, F&& f) {
  const int y = g / GPR;
  const int x0 = (g - y * GPR) * 4;
  const float* rm = p + y * Wd + x0;
  const float4 mq = *(const float4*)rm;
  const float ml = (x0 > 0) ? rm[-1] : -INFINITY;
  const float mr = (x0 + 4 < Wd) ? rm[4] : -INFINITY;
  float4 tq; float tl, tr;
  if (y > 0) {
    const float* rt = rm - Wd;
    tq = *(const float4*)rt;
    tl = (x0 > 0) ? rt[-1] : -INFINITY;
    tr = (x0 + 4 < Wd) ? rt[4] : -INFINITY;
  } else {
    tq.x = tq.y = tq.z = tq.w = -INFINITY; tl = -INFINITY; tr = -INFINITY;
  }
  float4 bq; float bl, br;
  if (y < Hd - 1) {
    const float* rb = rm + Wd;
    bq = *(const float4*)rb;
    bl = (x0 > 0) ? rb[-1] : -INFINITY;
    br = (x0 + 4 < Wd) ? rb[4] : -INFINITY;
  } else {
    bq.x = bq.y = bq.z = bq.w = -INFINITY; bl = -INFINITY; br = -INFINITY;
  }
  const float c0 = fmax3(tl, ml, bl);
  const float c1 = fmax3(tq.x, mq.x, bq.x);
  const float c2 = fmax3(tq.y, mq.y, bq.y);
  const float c3 = fmax3(tq.z, mq.z, bq.z);
  const float c4 = fmax3(tq.w, mq.w, bq.w);
  const float c5 = fmax3(tr, mr, br);
  const int base = y * Wd + x0;
  if (mq.x == fmax3(c0, c1, c2)) f(__float_as_uint(mq.x), base + 0);
  if (mq.y == fmax3(c1, c2, c3)) f(__float_as_uint(mq.y), base + 1);
  if (mq.z == fmax3(c2, c3, c4)) f(__float_as_uint(mq.z), base + 2);
  if (mq.w == fmax3(c3, c4, c5)) f(__float_as_uint(mq.w), base + 3);
}

template <typename F>
__device__ inline void for_each_peak_plane(const float* __restrict__ p, int tid,
                                           int nth, F&& f) {
  for (int g = tid; g < GPP; g += nth) peaks_in_group(p, g, f);
}

// key = (bits << 32) | ~idx : strict u64 '>' == (value desc, idx asc).
__device__ inline unsigned long long mk_key(unsigned int bits, int idx) {
  return ((unsigned long long)bits << 32) | (unsigned int)~idx;
}

// Monotone bucket over value bits; ~uniform on [0.995, 1.0); clamped outside.
__device__ inline int bucket_of(unsigned int bits) {
  const unsigned int base = __float_as_uint(0.995f);
  if (bits <= base) return 0;
  unsigned int d = (bits - base) >> 9;
  return d > 255u ? 255 : (int)d;
}

// ---------------------------------------------------------------------------
// 16-px row segment, all named fields (registers only — no arrays, R2 lesson).
// ---------------------------------------------------------------------------
struct Row16 {
  float4 q0, q1, q2, q3;
  float l, r;
};

__device__ inline Row16 load_row16(const float* __restrict__ rp, int x0, bool valid) {
  Row16 o;
  if (valid) {
    o.q0 = *(const float4*)(rp);
    o.q1 = *(const float4*)(rp + 4);
    o.q2 = *(const float4*)(rp + 8);
    o.q3 = *(const float4*)(rp + 12);
    o.l = (x0 > 0) ? rp[-1] : -INFINITY;
    o.r = (x0 + 16 < Wd) ? rp[16] : -INFINITY;
  } else {
    o.q0.x = o.q0.y = o.q0.z = o.q0.w = -INFINITY;
    o.q1 = o.q0; o.q2 = o.q0; o.q3 = o.q0;
    o.l = -INFINITY; o.r = -INFINITY;
  }
  return o;
}

__device__ inline float4 max3v(const float4 a, const float4 b, const float4 c) {
  float4 o;
  o.x = fmax3(a.x, b.x, c.x);
  o.y = fmax3(a.y, b.y, c.y);
  o.z = fmax3(a.z, b.z, c.z);
  o.w = fmax3(a.w, b.w, c.w);
  return o;
}

// ---------------------------------------------------------------------------
// Kernel 1: scan. 96 planes x 30 blocks x 256 threads, one 16-px strip per
// thread (18 VMEM per 16 px — R4's 4-px version paid 36, VMEM-issue bound).
// LDS atomics only; fixed per-block global segment + plain count store.
// ---------------------------------------------------------------------------
__global__ __launch_bounds__(256) void scan_kernel(
    const float* __restrict__ heat,
    int* __restrict__ counts,                 // [NPL*SEGBLK]
    unsigned long long* __restrict__ segkey) {// [NPL*SEGBLK][SEGCAP]
  const int blk = blockIdx.x;
  const int plane = blk / SEGBLK;
  const int sub = blk - plane * SEGBLK;
  __shared__ unsigned long long s_k[SEGCAP];
  __shared__ int s_n;
  if (threadIdx.x == 0) s_n = 0;
  __syncthreads();

  const int strip = sub * 256 + threadIdx.x;   // < SPP
  const int y = strip / SPR;
  const int x0 = (strip - y * SPR) * 16;
  const float* pm = heat + (size_t)plane * HWp + y * Wd + x0;

  const Row16 m = load_row16(pm, x0, true);
  const Row16 t = load_row16(pm - Wd, x0, y > 0);
  const Row16 b = load_row16(pm + Wd, x0, y < Hd - 1);

  // column maxes over the 3 rows
  const float cl = fmax3(t.l, m.l, b.l);
  const float cr = fmax3(t.r, m.r, b.r);
  const float4 c0 = max3v(t.q0, m.q0, b.q0);
  const float4 c1 = max3v(t.q1, m.q1, b.q1);
  const float4 c2 = max3v(t.q2, m.q2, b.q2);
  const float4 c3 = max3v(t.q3, m.q3, b.q3);

  const float TH = 0.995f;
  const int base = y * Wd + x0;
#define EMIT(V, W0, W1, W2, J)                                         \
  if ((V) >= TH && (V) == fmax3((W0), (W1), (W2))) {                   \
    int slot = atomicAdd(&s_n, 1);                                     \
    if (slot < SEGCAP) s_k[slot] = mk_key(__float_as_uint(V), base + (J)); \
  }
  EMIT(m.q0.x, cl,   c0.x, c0.y, 0)
  EMIT(m.q0.y, c0.x, c0.y, c0.z, 1)
  EMIT(m.q0.z, c0.y, c0.z, c0.w, 2)
  EMIT(m.q0.w, c0.z, c0.w, c1.x, 3)
  EMIT(m.q1.x, c0.w, c1.x, c1.y, 4)
  EMIT(m.q1.y, c1.x, c1.y, c1.z, 5)
  EMIT(m.q1.z, c1.y, c1.z, c1.w, 6)
  EMIT(m.q1.w, c1.z, c1.w, c2.x, 7)
  EMIT(m.q2.x, c1.w, c2.x, c2.y, 8)
  EMIT(m.q2.y, c2.x, c2.y, c2.z, 9)
  EMIT(m.q2.z, c2.y, c2.z, c2.w, 10)
  EMIT(m.q2.w, c2.z, c2.w, c3.x, 11)
  EMIT(m.q3.x, c2.w, c3.x, c3.y, 12)
  EMIT(m.q3.y, c3.x, c3.y, c3.z, 13)
  EMIT(m.q3.z, c3.y, c3.z, c3.w, 14)
  EMIT(m.q3.w, c3.z, c3.w, cr,   15)
#undef EMIT

  __syncthreads();
  const int n = s_n;
  if (threadIdx.x == 0) counts[blk] = n;  // unclamped: overflow detectable
  const int nn = n < SEGCAP ? n : SEGCAP;
  if (threadIdx.x < nn)
    segkey[(size_t)blk * SEGCAP + threadIdx.x] = s_k[threadIdx.x];
}

// ---------------------------------------------------------------------------
// Kernel 2: fused per-class counting-sort rank (O(M)) + batch rank + decode.
// 32 blocks (one per batch) x 256 threads.
// ---------------------------------------------------------------------------
__device__ inline void inv3(const float* m, float* o) {
  float a = m[0], b = m[1], c = m[2];
  float d = m[3], e = m[4], f = m[5];
  float g = m[6], h = m[7], i = m[8];
  float A = e * i - f * h;
  float B = -(d * i - f * g);
  float C = d * h - e * g;
  float det = a * A + b * B + c * C;
  float id = 1.0f / det;
  o[0] = A * id;            o[1] = -(b * i - c * h) * id; o[2] = (b * f - c * e) * id;
  o[3] = B * id;            o[4] = (a * i - c * g) * id;  o[5] = -(a * f - c * d) * id;
  o[6] = C * id;            o[7] = -(a * h - b * g) * id; o[8] = (a * e - b * d) * id;
}

__device__ inline float wrap_pi(float a) {
  if (a > PI_F) return a - 2.0f * PI_F;
  if (a < -PI_F) return a + 2.0f * PI_F;
  return a;
}

__constant__ float DIM_REF_C[9] = {3.88f, 1.63f, 1.53f,
                                   0.84f, 1.76f, 0.66f,
                                   1.78f, 1.52f, 1.78f};

__global__ __launch_bounds__(256) void rank_decode_kernel(
    const float* __restrict__ heat,
    const int* __restrict__ counts,
    const unsigned long long* __restrict__ segkey,
    const float* __restrict__ regr,      // [B][8][HWp]
    const float* __restrict__ trans_mat, // [B][3][3]
    const float* __restrict__ K_mat,     // [B][3][3]
    const float* __restrict__ img_size,  // [B][2]
    float* __restrict__ out) {           // [B*50][14]
  const int b = blockIdx.x;
  const int tid = threadIdx.x;

  __shared__ unsigned long long s_key[CAP];   // raw candidates
  __shared__ unsigned long long g_key[CAP];   // bucket-grouped
  __shared__ int s_off[SEGBLK + 1];
  __shared__ int cnt[RBK], suf[RBK], cur[RBK];
  __shared__ unsigned int fb_hist[1024];
  __shared__ float cls_sc[NCLS * KTOP];
  __shared__ int cls_pi[NCLS * KTOP];
  __shared__ int sel[KTOP];
  __shared__ int s_flag, s_cnt, s_B, s_above, s_T;

  for (int c = 0; c < NCLS; ++c) {
    const int plane = b * NCLS + c;
    __syncthreads();  // protect s_key/g_key reuse across classes
    if (tid == 0) { s_flag = 0; s_off[0] = 0; }
    __syncthreads();
    if (tid < SEGBLK) {
      int n = counts[plane * SEGBLK + tid];
      if (n > SEGCAP) { atomicOr(&s_flag, 1); n = SEGCAP; }
      s_off[tid + 1] = n;
    }
    __syncthreads();
    if (tid == 0) {
      int acc = 0;
      for (int i = 1; i <= SEGBLK; ++i) { acc += s_off[i]; s_off[i] = acc; }
    }
    __syncthreads();
    int M = s_off[SEGBLK];
    const bool fast = (s_flag == 0) && (M >= KTOP) && (M <= CAP);

    if (fast) {
      // Parallel staging: flattened (segment, slot) loop, coalesced reads.
      const unsigned long long* pk = segkey + (size_t)plane * SEGBLK * SEGCAP;
      for (int i = tid; i < SEGBLK * SEGCAP; i += 256) {
        const int s = i >> 6;       // / SEGCAP
        const int j = i & (SEGCAP - 1);
        const int o = s_off[s];
        const int n = s_off[s + 1] - o;
        if (j < n) s_key[o + j] = pk[(size_t)s * SEGCAP + j];
      }
      __syncthreads();
    } else {
      // Exact radix-select rescan (values >= 0); never triggers on this data.
      const float* p = heat + (size_t)plane * HWp;
      for (int i = tid; i < 1024; i += 256) fb_hist[i] = 0;
      __syncthreads();
      for_each_peak_plane(p, tid, 256, [&](unsigned int bits, int idx) {
        unsigned int bkt = bits >> 20; if (bkt > 1023u) bkt = 1023u;
        atomicAdd(&fb_hist[bkt], 1u);
      });
      __syncthreads();
      if (tid == 0) {
        int acc = 0, Bs = -1;
        for (int bkt = 1023; bkt >= 0; --bkt) {
          int cc = (int)fb_hist[bkt];
          if (acc + cc >= KTOP) { Bs = bkt; s_above = acc; break; }
          acc += cc;
        }
        s_B = Bs;
        if (Bs < 0) s_above = acc;
      }
      __syncthreads();
      const int Bs = s_B;
      unsigned int T;
      if (Bs < 0) {
        T = 0;  // fewer than 50 peaks total: take them all
      } else {
        for (int i = tid; i < 1024; i += 256) fb_hist[i] = 0;
        __syncthreads();
        for_each_peak_plane(p, tid, 256, [&](unsigned int bits, int idx) {
          unsigned int bkt = bits >> 20; if (bkt > 1023u) bkt = 1023u;
          if ((int)bkt == Bs) atomicAdd(&fb_hist[(bits >> 10) & 1023], 1u);
        });
        __syncthreads();
        if (tid == 0) {
          int acc = s_above, Ss = 0;
          for (int sb = 1023; sb >= 0; --sb) {
            int cc = (int)fb_hist[sb];
            if (acc + cc >= KTOP) { Ss = sb; break; }
            acc += cc;
          }
          s_T = (int)(((unsigned int)Bs << 20) | ((unsigned int)Ss << 10));
        }
        __syncthreads();
        T = (unsigned int)s_T;
      }
      if (tid == 0) s_cnt = 0;
      __syncthreads();
      for_each_peak_plane(p, tid, 256, [&](unsigned int bits, int idx) {
        if (bits >= T) {
          int slot = atomicAdd(&s_cnt, 1);
          if (slot < CAP) s_key[slot] = mk_key(bits, idx);
        }
      });
      __syncthreads();
      M = s_cnt < CAP ? s_cnt : CAP;
    }

    // ---- O(M) counting-sort rank: exact (value desc, idx asc) order. ----
    for (int i = tid; i < RBK; i += 256) { cnt[i] = 0; cur[i] = 0; }
    __syncthreads();
    for (int i = tid; i < M; i += 256)
      atomicAdd(&cnt[bucket_of((unsigned int)(s_key[i] >> 32))], 1);
    __syncthreads();
    if (tid == 0) {
      int acc = 0;
      for (int bq = RBK - 1; bq >= 0; --bq) { suf[bq] = acc; acc += cnt[bq]; }
    }
    __syncthreads();
    for (int i = tid; i < M; i += 256) {
      const unsigned long long k = s_key[i];
      const int bq = bucket_of((unsigned int)(k >> 32));
      const int slot = suf[bq] + atomicAdd(&cur[bq], 1);
      g_key[slot] = k;
    }
    __syncthreads();
    for (int i = tid; i < M; i += 256) {
      const unsigned long long k = g_key[i];
      const int bq = bucket_of((unsigned int)(k >> 32));
      const int st = suf[bq];
      const int nb = cnt[bq];
      int rank = st;
      for (int t = st; t < st + nb; ++t) rank += (g_key[t] > k);
      if (rank < KTOP) {
        cls_sc[c * KTOP + rank] = __uint_as_float((unsigned int)(k >> 32));
        cls_pi[c * KTOP + rank] = (int)~((unsigned int)k);
      }
    }
    for (int s2 = M + tid; s2 < KTOP; s2 += 256) {
      cls_sc[c * KTOP + s2] = 0.0f;
      cls_pi[c * KTOP + s2] = 0;
    }
  }
  __syncthreads();

  // Batch-level top-50 over 150 scores (tie: lower flattened position wins).
  if (tid < NCLS * KTOP) {
    const float v = cls_sc[tid];
    int rank = 0;
    for (int j = 0; j < NCLS * KTOP; ++j) {
      const float w = cls_sc[j];
      rank += (w > v) || (w == v && j < tid);
    }
    if (rank < KTOP) sel[rank] = tid;
  }
  __syncthreads();

  if (tid < KTOP) {
    const int i = sel[tid];
    const int cls = i / KTOP;
    const float score = cls_sc[i];
    const int ind = cls_pi[i];
    const float ys = (float)(ind / Wd);
    const float xs = (float)(ind - (ind / Wd) * Wd);

    const float* rb = regr + (size_t)b * 8 * HWp + ind;
    const float r0 = rb[0 * HWp], r1 = rb[1 * HWp], r2 = rb[2 * HWp], r3 = rb[3 * HWp];
    const float r4 = rb[4 * HWp], r5 = rb[5 * HWp], r6 = rb[6 * HWp], r7 = rb[7 * HWp];

    float tm[9], km[9], tmi[9], kmi[9];
#pragma unroll
    for (int q = 0; q < 9; ++q) { tm[q] = trans_mat[b * 9 + q]; km[q] = K_mat[b * 9 + q]; }
    inv3(tm, tmi);
    inv3(km, kmi);

    const float px = xs + r1, py = ys + r2;
    const float gx = tmi[0] * px + tmi[1] * py + tmi[2];
    const float gy = tmi[3] * px + tmi[4] * py + tmi[5];
    const float gz = tmi[6] * px + tmi[7] * py + tmi[8];
    const float depth = r0 * 16.32f + 28.01f;
    const float qx = gx * depth, qy = gy * depth, qz = gz * depth;
    const float lx = kmi[0] * qx + kmi[1] * qy + kmi[2] * qz;
    float ly = kmi[3] * qx + kmi[4] * qy + kmi[5] * qz;
    const float lz = kmi[6] * qx + kmi[7] * qy + kmi[8] * qz;

    const float d0 = expf(r3) * DIM_REF_C[cls * 3 + 0];
    const float d1 = expf(r4) * DIM_REF_C[cls * 3 + 1];
    const float d2 = expf(r5) * DIM_REF_C[cls * 3 + 2];
    ly += d1 * 0.5f;

    const float ray = atanf(lx / (lz + 1e-7f));
    float alpha = atanf(r6 / (r7 + 1e-7f));
    alpha += (r7 >= 0.0f) ? -PI_F * 0.5f : PI_F * 0.5f;
    const float roty = wrap_pi(alpha + ray);
    alpha = wrap_pi(alpha);

    const float SX[8] = {-0.5f, 0.5f, 0.5f, 0.5f, 0.5f, -0.5f, -0.5f, -0.5f};
    const float SY[8] = {-1.0f, -1.0f, 0.0f, 0.0f, -1.0f, -1.0f, 0.0f, 0.0f};
    const float SZ[8] = {-0.5f, -0.5f, -0.5f, 0.5f, 0.5f, 0.5f, 0.5f, -0.5f};
    const float cr = cosf(roty), sr = sinf(roty);
    float minx = INFINITY, maxx = -INFINITY, miny = INFINITY, maxy = -INFINITY;
#pragma unroll
    for (int j = 0; j < 8; ++j) {
      const float ax = d0 * SX[j], ay = d1 * SY[j], az = d2 * SZ[j];
      const float cx = cr * ax + sr * az + lx;
      const float cy = ay + ly;
      const float cz = -sr * ax + cr * az + lz;
      const float ppx = km[0] * cx + km[1] * cy + km[2] * cz;
      const float ppy = km[3] * cx + km[4] * cy + km[5] * cz;
      const float ppz = km[6] * cx + km[7] * cy + km[8] * cz;
      const float X = ppx / ppz, Y = ppy / ppz;
      minx = fminf(minx, X); maxx = fmaxf(maxx, X);
      miny = fminf(miny, Y); maxy = fmaxf(maxy, Y);
    }
    const float Wi = img_size[b * 2 + 0], Hi = img_size[b * 2 + 1];
    const float xmin = fminf(fmaxf(minx, 0.0f), Wi);
    const float ymin = fminf(fmaxf(miny, 0.0f), Hi);
    const float xmax = fminf(fmaxf(maxx, 0.0f), Wi);
    const float ymax = fminf(fmaxf(maxy, 0.0f), Hi);

    float* o = out + (size_t)(b * KTOP + tid) * 14;
    if (score > 0.25f) {
      o[0] = (float)cls; o[1] = alpha;
      o[2] = xmin; o[3] = ymin; o[4] = xmax; o[5] = ymax;
      o[6] = d1; o[7] = d2; o[8] = d0;   // dims rolled by -1
      o[9] = lx; o[10] = ly; o[11] = lz;
      o[12] = roty; o[13] = score;
    } else {
#pragma unroll
      for (int q = 0; q < 14; ++q) o[q] = 0.0f;
    }
  }
}

// ---------------------------------------------------------------------------

extern "C" void kernel_launch(void* const* d_in, const int* in_sizes, int n_in,
                              void* d_out, int out_size, void* d_ws, size_t ws_size,
                              hipStream_t stream) {
  const float* heat = (const float*)d_in[0];  // [32,3,192,640]
  const float* regr = (const float*)d_in[1];  // [32,8,192,640]
  const float* tmat = (const float*)d_in[2];  // [32,3,3]
  const float* kmat = (const float*)d_in[3];  // [32,3,3]
  const float* isz = (const float*)d_in[4];   // [32,2]

  // Workspace: counts (NPL*SEGBLK ints = 11520 B, 8-aligned) then u64
  // segments (NPL*SEGBLK*SEGCAP*8 = 1.47 MB).
  char* ws = (char*)d_ws;
  int* counts = (int*)ws;
  unsigned long long* segkey = (unsigned long long*)(ws + NPL * SEGBLK * 4);

  scan_kernel<<<NPL * SEGBLK, 256, 0, stream>>>(heat, counts, segkey);
  rank_decode_kernel<<<NB, 256, 0, stream>>>(heat, counts, segkey,
                                             regr, tmat, kmat, isz, (float*)d_out);
}

// Round 6
// 212.474 us; speedup vs baseline: 1.0854x; 1.0854x over previous
//
#include <hip/hip_runtime.h>
#include <math.h>

#define Hd 192
#define Wd 640
#define HWp (Hd * Wd)
#define NCLS 3
#define KTOP 50
#define NB 32
#define NPL (NB * NCLS)   // 96 planes
#define GPR 160           // 4-pixel groups per row (fallback scanner)
#define GPP (HWp / 4)     // 30720 groups per plane (fallback scanner)
#define SPR 40            // 16-px strips per row
#define SEGBLK 30         // scan blocks per plane (256 strips = 4096 px each)
#define SEGCAP 64         // candidate slots per scan block (E~20, 10 sigma)
#define CAP 2048          // per-plane candidate cap for ranking
#define RBK 256           // rank buckets
#define PI_F 3.14159265358979f

__device__ inline float fmax3(float a, float b, float c) {
  return fmaxf(fmaxf(a, b), c);
}

// ---------------------------------------------------------------------------
// Fallback 4-px-group peak scanner (exact radix rescan path only).
// ---------------------------------------------------------------------------
template <typename F>
__device__ inline void peaks_in_group(const float* __restrict__ p, int g, F&& f) {
  const int y = g / GPR;
  const int x0 = (g - y * GPR) * 4;
  const float* rm = p + y * Wd + x0;
  const float4 mq = *(const float4*)rm;
  const float ml = (x0 > 0) ? rm[-1] : -INFINITY;
  const float mr = (x0 + 4 < Wd) ? rm[4] : -INFINITY;
  float4 tq; float tl, tr;
  if (y > 0) {
    const float* rt = rm - Wd;
    tq = *(const float4*)rt;
    tl = (x0 > 0) ? rt[-1] : -INFINITY;
    tr = (x0 + 4 < Wd) ? rt[4] : -INFINITY;
  } else {
    tq.x = tq.y = tq.z = tq.w = -INFINITY; tl = -INFINITY; tr = -INFINITY;
  }
  float4 bq; float bl, br;
  if (y < Hd - 1) {
    const float* rb = rm + Wd;
    bq = *(const float4*)rb;
    bl = (x0 > 0) ? rb[-1] : -INFINITY;
    br = (x0 + 4 < Wd) ? rb[4] : -INFINITY;
  } else {
    bq.x = bq.y = bq.z = bq.w = -INFINITY; bl = -INFINITY; br = -INFINITY;
  }
  const float c0 = fmax3(tl, ml, bl);
  const float c1 = fmax3(tq.x, mq.x, bq.x);
  const float c2 = fmax3(tq.y, mq.y, bq.y);
  const float c3 = fmax3(tq.z, mq.z, bq.z);
  const float c4 = fmax3(tq.w, mq.w, bq.w);
  const float c5 = fmax3(tr, mr, br);
  const int base = y * Wd + x0;
  if (mq.x == fmax3(c0, c1, c2)) f(__float_as_uint(mq.x), base + 0);
  if (mq.y == fmax3(c1, c2, c3)) f(__float_as_uint(mq.y), base + 1);
  if (mq.z == fmax3(c2, c3, c4)) f(__float_as_uint(mq.z), base + 2);
  if (mq.w == fmax3(c3, c4, c5)) f(__float_as_uint(mq.w), base + 3);
}

template <typename F>
__device__ inline void for_each_peak_plane(const float* __restrict__ p, int tid,
                                           int nth, F&& f) {
  for (int g = tid; g < GPP; g += nth) peaks_in_group(p, g, f);
}

// key = (bits << 32) | ~idx : strict u64 '>' == (value desc, idx asc).
__device__ inline unsigned long long mk_key(unsigned int bits, int idx) {
  return ((unsigned long long)bits << 32) | (unsigned int)~idx;
}

// Monotone bucket over value bits; ~uniform on [0.995, 1.0); clamped outside.
__device__ inline int bucket_of(unsigned int bits) {
  const unsigned int base = __float_as_uint(0.995f);
  if (bits <= base) return 0;
  unsigned int d = (bits - base) >> 9;
  return d > 255u ? 255 : (int)d;
}

// ---------------------------------------------------------------------------
// 16-px row segment, all named fields (registers only — no arrays, R2 lesson).
// ---------------------------------------------------------------------------
struct Row16 {
  float4 q0, q1, q2, q3;
  float l, r;
};

__device__ inline Row16 load_row16(const float* __restrict__ rp, int x0, bool valid) {
  Row16 o;
  if (valid) {
    o.q0 = *(const float4*)(rp);
    o.q1 = *(const float4*)(rp + 4);
    o.q2 = *(const float4*)(rp + 8);
    o.q3 = *(const float4*)(rp + 12);
    o.l = (x0 > 0) ? rp[-1] : -INFINITY;
    o.r = (x0 + 16 < Wd) ? rp[16] : -INFINITY;
  } else {
    o.q0.x = o.q0.y = o.q0.z = o.q0.w = -INFINITY;
    o.q1 = o.q0; o.q2 = o.q0; o.q3 = o.q0;
    o.l = -INFINITY; o.r = -INFINITY;
  }
  return o;
}

__device__ inline float4 max3v(const float4 a, const float4 b, const float4 c) {
  float4 o;
  o.x = fmax3(a.x, b.x, c.x);
  o.y = fmax3(a.y, b.y, c.y);
  o.z = fmax3(a.z, b.z, c.z);
  o.w = fmax3(a.w, b.w, c.w);
  return o;
}

// ---------------------------------------------------------------------------
// Kernel 1: scan. 96 planes x 30 blocks x 256 threads, one 16-px strip per
// thread. LDS atomics only; fixed per-block global segment + count store.
// ---------------------------------------------------------------------------
__global__ __launch_bounds__(256) void scan_kernel(
    const float* __restrict__ heat,
    int* __restrict__ counts,                 // [NPL*SEGBLK]
    unsigned long long* __restrict__ segkey) {// [NPL*SEGBLK][SEGCAP]
  const int blk = blockIdx.x;
  const int plane = blk / SEGBLK;
  const int sub = blk - plane * SEGBLK;
  __shared__ unsigned long long s_k[SEGCAP];
  __shared__ int s_n;
  if (threadIdx.x == 0) s_n = 0;
  __syncthreads();

  const int strip = sub * 256 + threadIdx.x;
  const int y = strip / SPR;
  const int x0 = (strip - y * SPR) * 16;
  const float* pm = heat + (size_t)plane * HWp + y * Wd + x0;

  const Row16 m = load_row16(pm, x0, true);
  const Row16 t = load_row16(pm - Wd, x0, y > 0);
  const Row16 b = load_row16(pm + Wd, x0, y < Hd - 1);

  const float cl = fmax3(t.l, m.l, b.l);
  const float cr = fmax3(t.r, m.r, b.r);
  const float4 c0 = max3v(t.q0, m.q0, b.q0);
  const float4 c1 = max3v(t.q1, m.q1, b.q1);
  const float4 c2 = max3v(t.q2, m.q2, b.q2);
  const float4 c3 = max3v(t.q3, m.q3, b.q3);

  const float TH = 0.995f;
  const int base = y * Wd + x0;
#define EMIT(V, W0, W1, W2, J)                                         \
  if ((V) >= TH && (V) == fmax3((W0), (W1), (W2))) {                   \
    int slot = atomicAdd(&s_n, 1);                                     \
    if (slot < SEGCAP) s_k[slot] = mk_key(__float_as_uint(V), base + (J)); \
  }
  EMIT(m.q0.x, cl,   c0.x, c0.y, 0)
  EMIT(m.q0.y, c0.x, c0.y, c0.z, 1)
  EMIT(m.q0.z, c0.y, c0.z, c0.w, 2)
  EMIT(m.q0.w, c0.z, c0.w, c1.x, 3)
  EMIT(m.q1.x, c0.w, c1.x, c1.y, 4)
  EMIT(m.q1.y, c1.x, c1.y, c1.z, 5)
  EMIT(m.q1.z, c1.y, c1.z, c1.w, 6)
  EMIT(m.q1.w, c1.z, c1.w, c2.x, 7)
  EMIT(m.q2.x, c1.w, c2.x, c2.y, 8)
  EMIT(m.q2.y, c2.x, c2.y, c2.z, 9)
  EMIT(m.q2.z, c2.y, c2.z, c2.w, 10)
  EMIT(m.q2.w, c2.z, c2.w, c3.x, 11)
  EMIT(m.q3.x, c2.w, c3.x, c3.y, 12)
  EMIT(m.q3.y, c3.x, c3.y, c3.z, 13)
  EMIT(m.q3.z, c3.y, c3.z, c3.w, 14)
  EMIT(m.q3.w, c3.z, c3.w, cr,   15)
#undef EMIT

  __syncthreads();
  const int n = s_n;
  if (threadIdx.x == 0) counts[blk] = n;
  const int nn = n < SEGCAP ? n : SEGCAP;
  if (threadIdx.x < nn)
    segkey[(size_t)blk * SEGCAP + threadIdx.x] = s_k[threadIdx.x];
}

// ---------------------------------------------------------------------------
// Kernel 2: per-plane counting-sort rank. 96 blocks (one per plane) — R5 had
// 32 blocks x 3 serial classes; this is 3x shallower and 3x wider.
// ---------------------------------------------------------------------------
__global__ __launch_bounds__(256) void plane_rank_kernel(
    const float* __restrict__ heat,
    const int* __restrict__ counts,
    const unsigned long long* __restrict__ segkey,
    float* __restrict__ out_scores,  // [96][50]
    int* __restrict__ out_inds) {    // [96][50]
  const int plane = blockIdx.x;
  const int tid = threadIdx.x;

  __shared__ unsigned long long s_key[CAP];
  __shared__ unsigned long long g_key[CAP];
  __shared__ int s_off[SEGBLK + 1];
  __shared__ int cnt[RBK], suf[RBK], cur[RBK];
  __shared__ unsigned int fb_hist[1024];
  __shared__ int s_flag, s_cnt, s_B, s_above, s_T;

  if (tid == 0) { s_flag = 0; s_off[0] = 0; }
  __syncthreads();
  if (tid < SEGBLK) {
    int n = counts[plane * SEGBLK + tid];
    if (n > SEGCAP) { atomicOr(&s_flag, 1); n = SEGCAP; }
    s_off[tid + 1] = n;
  }
  __syncthreads();
  if (tid == 0) {
    int acc = 0;
    for (int i = 1; i <= SEGBLK; ++i) { acc += s_off[i]; s_off[i] = acc; }
  }
  __syncthreads();
  int M = s_off[SEGBLK];
  const bool fast = (s_flag == 0) && (M >= KTOP) && (M <= CAP);

  if (fast) {
    const unsigned long long* pk = segkey + (size_t)plane * SEGBLK * SEGCAP;
    for (int i = tid; i < SEGBLK * SEGCAP; i += 256) {
      const int s = i >> 6;       // / SEGCAP
      const int j = i & (SEGCAP - 1);
      const int o = s_off[s];
      const int n = s_off[s + 1] - o;
      if (j < n) s_key[o + j] = pk[(size_t)s * SEGCAP + j];
    }
    __syncthreads();
  } else {
    // Exact radix-select rescan (values >= 0); never triggers on this data.
    const float* p = heat + (size_t)plane * HWp;
    for (int i = tid; i < 1024; i += 256) fb_hist[i] = 0;
    __syncthreads();
    for_each_peak_plane(p, tid, 256, [&](unsigned int bits, int idx) {
      unsigned int bkt = bits >> 20; if (bkt > 1023u) bkt = 1023u;
      atomicAdd(&fb_hist[bkt], 1u);
    });
    __syncthreads();
    if (tid == 0) {
      int acc = 0, Bs = -1;
      for (int bkt = 1023; bkt >= 0; --bkt) {
        int cc = (int)fb_hist[bkt];
        if (acc + cc >= KTOP) { Bs = bkt; s_above = acc; break; }
        acc += cc;
      }
      s_B = Bs;
      if (Bs < 0) s_above = acc;
    }
    __syncthreads();
    const int Bs = s_B;
    unsigned int T;
    if (Bs < 0) {
      T = 0;  // fewer than 50 peaks total: take them all
    } else {
      for (int i = tid; i < 1024; i += 256) fb_hist[i] = 0;
      __syncthreads();
      for_each_peak_plane(p, tid, 256, [&](unsigned int bits, int idx) {
        unsigned int bkt = bits >> 20; if (bkt > 1023u) bkt = 1023u;
        if ((int)bkt == Bs) atomicAdd(&fb_hist[(bits >> 10) & 1023], 1u);
      });
      __syncthreads();
      if (tid == 0) {
        int acc = s_above, Ss = 0;
        for (int sb = 1023; sb >= 0; --sb) {
          int cc = (int)fb_hist[sb];
          if (acc + cc >= KTOP) { Ss = sb; break; }
          acc += cc;
        }
        s_T = (int)(((unsigned int)Bs << 20) | ((unsigned int)Ss << 10));
      }
      __syncthreads();
      T = (unsigned int)s_T;
    }
    if (tid == 0) s_cnt = 0;
    __syncthreads();
    for_each_peak_plane(p, tid, 256, [&](unsigned int bits, int idx) {
      if (bits >= T) {
        int slot = atomicAdd(&s_cnt, 1);
        if (slot < CAP) s_key[slot] = mk_key(bits, idx);
      }
    });
    __syncthreads();
    M = s_cnt < CAP ? s_cnt : CAP;
  }

  // ---- O(M) counting-sort rank: exact (value desc, idx asc) order. ----
  for (int i = tid; i < RBK; i += 256) { cnt[i] = 0; cur[i] = 0; }
  __syncthreads();
  for (int i = tid; i < M; i += 256)
    atomicAdd(&cnt[bucket_of((unsigned int)(s_key[i] >> 32))], 1);
  __syncthreads();
  if (tid == 0) {
    int acc = 0;
    for (int bq = RBK - 1; bq >= 0; --bq) { suf[bq] = acc; acc += cnt[bq]; }
  }
  __syncthreads();
  for (int i = tid; i < M; i += 256) {
    const unsigned long long k = s_key[i];
    const int bq = bucket_of((unsigned int)(k >> 32));
    const int slot = suf[bq] + atomicAdd(&cur[bq], 1);
    g_key[slot] = k;
  }
  __syncthreads();
  for (int i = tid; i < M; i += 256) {
    const unsigned long long k = g_key[i];
    const int bq = bucket_of((unsigned int)(k >> 32));
    const int st = suf[bq];
    const int nb = cnt[bq];
    int rank = st;
    for (int t = st; t < st + nb; ++t) rank += (g_key[t] > k);
    if (rank < KTOP) {
      out_scores[plane * KTOP + rank] = __uint_as_float((unsigned int)(k >> 32));
      out_inds[plane * KTOP + rank] = (int)~((unsigned int)k);
    }
  }
  __syncthreads();
  for (int s2 = M + tid; s2 < KTOP; s2 += 256) {
    out_scores[plane * KTOP + s2] = 0.0f;
    out_inds[plane * KTOP + s2] = 0;
  }
}

// ---------------------------------------------------------------------------
// Kernel 3: per-batch top-50 over the 150 class scores + full 3D decode.
// 32 blocks x 192 threads.
// ---------------------------------------------------------------------------
__device__ inline void inv3(const float* m, float* o) {
  float a = m[0], b = m[1], c = m[2];
  float d = m[3], e = m[4], f = m[5];
  float g = m[6], h = m[7], i = m[8];
  float A = e * i - f * h;
  float B = -(d * i - f * g);
  float C = d * h - e * g;
  float det = a * A + b * B + c * C;
  float id = 1.0f / det;
  o[0] = A * id;            o[1] = -(b * i - c * h) * id; o[2] = (b * f - c * e) * id;
  o[3] = B * id;            o[4] = (a * i - c * g) * id;  o[5] = -(a * f - c * d) * id;
  o[6] = C * id;            o[7] = -(a * h - b * g) * id; o[8] = (a * e - b * d) * id;
}

__device__ inline float wrap_pi(float a) {
  if (a > PI_F) return a - 2.0f * PI_F;
  if (a < -PI_F) return a + 2.0f * PI_F;
  return a;
}

__constant__ float DIM_REF_C[9] = {3.88f, 1.63f, 1.53f,
                                   0.84f, 1.76f, 0.66f,
                                   1.78f, 1.52f, 1.78f};

__global__ __launch_bounds__(192) void decode_kernel(
    const float* __restrict__ regr,      // [B][8][HWp]
    const float* __restrict__ trans_mat, // [B][3][3]
    const float* __restrict__ K_mat,     // [B][3][3]
    const float* __restrict__ img_size,  // [B][2]
    const float* __restrict__ ws_scores, // [96][50]
    const int* __restrict__ ws_inds,     // [96][50]
    float* __restrict__ out) {           // [B*50][14]
  const int b = blockIdx.x;
  const int tid = threadIdx.x;
  __shared__ float sc[NCLS * KTOP];
  __shared__ int pi[NCLS * KTOP];
  __shared__ int sel[KTOP];

  if (tid < NCLS * KTOP) {
    sc[tid] = ws_scores[b * NCLS * KTOP + tid];
    pi[tid] = ws_inds[b * NCLS * KTOP + tid];
  }
  __syncthreads();

  if (tid < NCLS * KTOP) {
    const float v = sc[tid];
    int rank = 0;
    for (int j = 0; j < NCLS * KTOP; ++j) {
      const float w = sc[j];
      rank += (w > v) || (w == v && j < tid);
    }
    if (rank < KTOP) sel[rank] = tid;
  }
  __syncthreads();

  if (tid < KTOP) {
    const int i = sel[tid];
    const int cls = i / KTOP;
    const float score = sc[i];
    const int ind = pi[i];
    const float ys = (float)(ind / Wd);
    const float xs = (float)(ind - (ind / Wd) * Wd);

    const float* rb = regr + (size_t)b * 8 * HWp + ind;
    const float r0 = rb[0 * HWp], r1 = rb[1 * HWp], r2 = rb[2 * HWp], r3 = rb[3 * HWp];
    const float r4 = rb[4 * HWp], r5 = rb[5 * HWp], r6 = rb[6 * HWp], r7 = rb[7 * HWp];

    float tm[9], km[9], tmi[9], kmi[9];
#pragma unroll
    for (int q = 0; q < 9; ++q) { tm[q] = trans_mat[b * 9 + q]; km[q] = K_mat[b * 9 + q]; }
    inv3(tm, tmi);
    inv3(km, kmi);

    const float px = xs + r1, py = ys + r2;
    const float gx = tmi[0] * px + tmi[1] * py + tmi[2];
    const float gy = tmi[3] * px + tmi[4] * py + tmi[5];
    const float gz = tmi[6] * px + tmi[7] * py + tmi[8];
    const float depth = r0 * 16.32f + 28.01f;
    const float qx = gx * depth, qy = gy * depth, qz = gz * depth;
    const float lx = kmi[0] * qx + kmi[1] * qy + kmi[2] * qz;
    float ly = kmi[3] * qx + kmi[4] * qy + kmi[5] * qz;
    const float lz = kmi[6] * qx + kmi[7] * qy + kmi[8] * qz;

    const float d0 = expf(r3) * DIM_REF_C[cls * 3 + 0];
    const float d1 = expf(r4) * DIM_REF_C[cls * 3 + 1];
    const float d2 = expf(r5) * DIM_REF_C[cls * 3 + 2];
    ly += d1 * 0.5f;

    const float ray = atanf(lx / (lz + 1e-7f));
    float alpha = atanf(r6 / (r7 + 1e-7f));
    alpha += (r7 >= 0.0f) ? -PI_F * 0.5f : PI_F * 0.5f;
    const float roty = wrap_pi(alpha + ray);
    alpha = wrap_pi(alpha);

    const float SX[8] = {-0.5f, 0.5f, 0.5f, 0.5f, 0.5f, -0.5f, -0.5f, -0.5f};
    const float SY[8] = {-1.0f, -1.0f, 0.0f, 0.0f, -1.0f, -1.0f, 0.0f, 0.0f};
    const float SZ[8] = {-0.5f, -0.5f, -0.5f, 0.5f, 0.5f, 0.5f, 0.5f, -0.5f};
    const float cr = cosf(roty), sr = sinf(roty);
    float minx = INFINITY, maxx = -INFINITY, miny = INFINITY, maxy = -INFINITY;
#pragma unroll
    for (int j = 0; j < 8; ++j) {
      const float ax = d0 * SX[j], ay = d1 * SY[j], az = d2 * SZ[j];
      const float cx = cr * ax + sr * az + lx;
      const float cy = ay + ly;
      const float cz = -sr * ax + cr * az + lz;
      const float ppx = km[0] * cx + km[1] * cy + km[2] * cz;
      const float ppy = km[3] * cx + km[4] * cy + km[5] * cz;
      const float ppz = km[6] * cx + km[7] * cy + km[8] * cz;
      const float X = ppx / ppz, Y = ppy / ppz;
      minx = fminf(minx, X); maxx = fmaxf(maxx, X);
      miny = fminf(miny, Y); maxy = fmaxf(maxy, Y);
    }
    const float Wi = img_size[b * 2 + 0], Hi = img_size[b * 2 + 1];
    const float xmin = fminf(fmaxf(minx, 0.0f), Wi);
    const float ymin = fminf(fmaxf(miny, 0.0f), Hi);
    const float xmax = fminf(fmaxf(maxx, 0.0f), Wi);
    const float ymax = fminf(fmaxf(maxy, 0.0f), Hi);

    float* o = out + (size_t)(b * KTOP + tid) * 14;
    if (score > 0.25f) {
      o[0] = (float)cls; o[1] = alpha;
      o[2] = xmin; o[3] = ymin; o[4] = xmax; o[5] = ymax;
      o[6] = d1; o[7] = d2; o[8] = d0;   // dims rolled by -1
      o[9] = lx; o[10] = ly; o[11] = lz;
      o[12] = roty; o[13] = score;
    } else {
#pragma unroll
      for (int q = 0; q < 14; ++q) o[q] = 0.0f;
    }
  }
}

// ---------------------------------------------------------------------------

extern "C" void kernel_launch(void* const* d_in, const int* in_sizes, int n_in,
                              void* d_out, int out_size, void* d_ws, size_t ws_size,
                              hipStream_t stream) {
  const float* heat = (const float*)d_in[0];  // [32,3,192,640]
  const float* regr = (const float*)d_in[1];  // [32,8,192,640]
  const float* tmat = (const float*)d_in[2];  // [32,3,3]
  const float* kmat = (const float*)d_in[3];  // [32,3,3]
  const float* isz = (const float*)d_in[4];   // [32,2]

  // Workspace layout:
  //   [0, 11520)          counts   (NPL*SEGBLK ints)
  //   [16384, +1.47MB)    segkey   (NPL*SEGBLK*SEGCAP u64, 8-aligned)
  //   then scores [96*50] f32, inds [96*50] i32
  char* ws = (char*)d_ws;
  int* counts = (int*)ws;
  unsigned long long* segkey = (unsigned long long*)(ws + 16384);
  char* after_seg = ws + 16384 + (size_t)NPL * SEGBLK * SEGCAP * 8;
  float* ws_scores = (float*)after_seg;
  int* ws_inds = (int*)(after_seg + NPL * KTOP * sizeof(float));

  scan_kernel<<<NPL * SEGBLK, 256, 0, stream>>>(heat, counts, segkey);
  plane_rank_kernel<<<NPL, 256, 0, stream>>>(heat, counts, segkey,
                                             ws_scores, ws_inds);
  decode_kernel<<<NB, 192, 0, stream>>>(regr, tmat, kmat, isz,
                                        ws_scores, ws_inds, (float*)d_out);
}

// Round 7
// 211.448 us; speedup vs baseline: 1.0906x; 1.0049x over previous
//
#include <hip/hip_runtime.h>
#include <math.h>

#define Hd 192
#define Wd 640
#define HWp (Hd * Wd)
#define NCLS 3
#define KTOP 50
#define NB 32
#define NPL (NB * NCLS)   // 96 planes
#define GPR 160           // 4-pixel groups per row (fallback scanner)
#define GPP (HWp / 4)     // 30720 groups per plane (fallback scanner)
#define SPR 40            // 16-px strips per row
#define SEGBLK 30         // scan blocks per plane (256 strips = 4096 px each)
#define SEGCAP 64         // candidate slots per scan block (E~20, 10 sigma)
#define CAP 2048          // per-plane candidate cap for ranking
#define RBK 256           // rank buckets
#define PI_F 3.14159265358979f

__device__ inline float fmax3(float a, float b, float c) {
  return fmaxf(fmaxf(a, b), c);
}

// ---------------------------------------------------------------------------
// Fallback 4-px-group peak scanner (exact radix rescan path only).
// ---------------------------------------------------------------------------
template <typename F>
__device__ inline void peaks_in_group(const float* __restrict__ p, int g, F&& f) {
  const int y = g / GPR;
  const int x0 = (g - y * GPR) * 4;
  const float* rm = p + y * Wd + x0;
  const float4 mq = *(const float4*)rm;
  const float ml = (x0 > 0) ? rm[-1] : -INFINITY;
  const float mr = (x0 + 4 < Wd) ? rm[4] : -INFINITY;
  float4 tq; float tl, tr;
  if (y > 0) {
    const float* rt = rm - Wd;
    tq = *(const float4*)rt;
    tl = (x0 > 0) ? rt[-1] : -INFINITY;
    tr = (x0 + 4 < Wd) ? rt[4] : -INFINITY;
  } else {
    tq.x = tq.y = tq.z = tq.w = -INFINITY; tl = -INFINITY; tr = -INFINITY;
  }
  float4 bq; float bl, br;
  if (y < Hd - 1) {
    const float* rb = rm + Wd;
    bq = *(const float4*)rb;
    bl = (x0 > 0) ? rb[-1] : -INFINITY;
    br = (x0 + 4 < Wd) ? rb[4] : -INFINITY;
  } else {
    bq.x = bq.y = bq.z = bq.w = -INFINITY; bl = -INFINITY; br = -INFINITY;
  }
  const float c0 = fmax3(tl, ml, bl);
  const float c1 = fmax3(tq.x, mq.x, bq.x);
  const float c2 = fmax3(tq.y, mq.y, bq.y);
  const float c3 = fmax3(tq.z, mq.z, bq.z);
  const float c4 = fmax3(tq.w, mq.w, bq.w);
  const float c5 = fmax3(tr, mr, br);
  const int base = y * Wd + x0;
  if (mq.x == fmax3(c0, c1, c2)) f(__float_as_uint(mq.x), base + 0);
  if (mq.y == fmax3(c1, c2, c3)) f(__float_as_uint(mq.y), base + 1);
  if (mq.z == fmax3(c2, c3, c4)) f(__float_as_uint(mq.z), base + 2);
  if (mq.w == fmax3(c3, c4, c5)) f(__float_as_uint(mq.w), base + 3);
}

template <typename F>
__device__ inline void for_each_peak_plane(const float* __restrict__ p, int tid,
                                           int nth, F&& f) {
  for (int g = tid; g < GPP; g += nth) peaks_in_group(p, g, f);
}

// key = (bits << 32) | ~idx : strict u64 '>' == (value desc, idx asc).
__device__ inline unsigned long long mk_key(unsigned int bits, int idx) {
  return ((unsigned long long)bits << 32) | (unsigned int)~idx;
}

// Monotone bucket over value bits; ~uniform on [0.995, 1.0); clamped outside.
__device__ inline int bucket_of(unsigned int bits) {
  const unsigned int base = __float_as_uint(0.995f);
  if (bits <= base) return 0;
  unsigned int d = (bits - base) >> 9;
  return d > 255u ? 255 : (int)d;
}

// ---------------------------------------------------------------------------
// 16-px row segment, all named fields (registers only — no arrays, R2 lesson).
// ---------------------------------------------------------------------------
struct Row16 {
  float4 q0, q1, q2, q3;
  float l, r;
};

__device__ inline Row16 load_row16(const float* __restrict__ rp, int x0, bool valid) {
  Row16 o;
  if (valid) {
    o.q0 = *(const float4*)(rp);
    o.q1 = *(const float4*)(rp + 4);
    o.q2 = *(const float4*)(rp + 8);
    o.q3 = *(const float4*)(rp + 12);
    o.l = (x0 > 0) ? rp[-1] : -INFINITY;
    o.r = (x0 + 16 < Wd) ? rp[16] : -INFINITY;
  } else {
    o.q0.x = o.q0.y = o.q0.z = o.q0.w = -INFINITY;
    o.q1 = o.q0; o.q2 = o.q0; o.q3 = o.q0;
    o.l = -INFINITY; o.r = -INFINITY;
  }
  return o;
}

__device__ inline float4 max3v(const float4 a, const float4 b, const float4 c) {
  float4 o;
  o.x = fmax3(a.x, b.x, c.x);
  o.y = fmax3(a.y, b.y, c.y);
  o.z = fmax3(a.z, b.z, c.z);
  o.w = fmax3(a.w, b.w, c.w);
  return o;
}

// ---------------------------------------------------------------------------
// Kernel 1: scan. 96 planes x 30 blocks x 256 threads, one 16-px strip per
// thread. LDS atomics only; fixed per-block global segment + count store.
// ---------------------------------------------------------------------------
__global__ __launch_bounds__(256) void scan_kernel(
    const float* __restrict__ heat,
    int* __restrict__ counts,                 // [NPL*SEGBLK]
    unsigned long long* __restrict__ segkey) {// [NPL*SEGBLK][SEGCAP]
  const int blk = blockIdx.x;
  const int plane = blk / SEGBLK;
  const int sub = blk - plane * SEGBLK;
  __shared__ unsigned long long s_k[SEGCAP];
  __shared__ int s_n;
  if (threadIdx.x == 0) s_n = 0;
  __syncthreads();

  const int strip = sub * 256 + threadIdx.x;
  const int y = strip / SPR;
  const int x0 = (strip - y * SPR) * 16;
  const float* pm = heat + (size_t)plane * HWp + y * Wd + x0;

  const Row16 m = load_row16(pm, x0, true);
  const Row16 t = load_row16(pm - Wd, x0, y > 0);
  const Row16 b = load_row16(pm + Wd, x0, y < Hd - 1);

  const float cl = fmax3(t.l, m.l, b.l);
  const float cr = fmax3(t.r, m.r, b.r);
  const float4 c0 = max3v(t.q0, m.q0, b.q0);
  const float4 c1 = max3v(t.q1, m.q1, b.q1);
  const float4 c2 = max3v(t.q2, m.q2, b.q2);
  const float4 c3 = max3v(t.q3, m.q3, b.q3);

  const float TH = 0.995f;
  const int base = y * Wd + x0;
#define EMIT(V, W0, W1, W2, J)                                         \
  if ((V) >= TH && (V) == fmax3((W0), (W1), (W2))) {                   \
    int slot = atomicAdd(&s_n, 1);                                     \
    if (slot < SEGCAP) s_k[slot] = mk_key(__float_as_uint(V), base + (J)); \
  }
  EMIT(m.q0.x, cl,   c0.x, c0.y, 0)
  EMIT(m.q0.y, c0.x, c0.y, c0.z, 1)
  EMIT(m.q0.z, c0.y, c0.z, c0.w, 2)
  EMIT(m.q0.w, c0.z, c0.w, c1.x, 3)
  EMIT(m.q1.x, c0.w, c1.x, c1.y, 4)
  EMIT(m.q1.y, c1.x, c1.y, c1.z, 5)
  EMIT(m.q1.z, c1.y, c1.z, c1.w, 6)
  EMIT(m.q1.w, c1.z, c1.w, c2.x, 7)
  EMIT(m.q2.x, c1.w, c2.x, c2.y, 8)
  EMIT(m.q2.y, c2.x, c2.y, c2.z, 9)
  EMIT(m.q2.z, c2.y, c2.z, c2.w, 10)
  EMIT(m.q2.w, c2.z, c2.w, c3.x, 11)
  EMIT(m.q3.x, c2.w, c3.x, c3.y, 12)
  EMIT(m.q3.y, c3.x, c3.y, c3.z, 13)
  EMIT(m.q3.z, c3.y, c3.z, c3.w, 14)
  EMIT(m.q3.w, c3.z, c3.w, cr,   15)
#undef EMIT

  __syncthreads();
  const int n = s_n;
  if (threadIdx.x == 0) counts[blk] = n;
  const int nn = n < SEGCAP ? n : SEGCAP;
  if (threadIdx.x < nn)
    segkey[(size_t)blk * SEGCAP + threadIdx.x] = s_k[threadIdx.x];
}

// ---------------------------------------------------------------------------
// Kernel 2: fused 3-plane-parallel rank + batch top-50 + 3D decode.
// 32 blocks x 768 threads: group g = tid>>8 ranks plane 3b+g in its own LDS
// arena (R5's version did the 3 classes SERIALLY — that was the regression).
// All __syncthreads are block-uniform: fast/fallback decisions live in LDS.
// ---------------------------------------------------------------------------
__device__ inline void inv3(const float* m, float* o) {
  float a = m[0], b = m[1], c = m[2];
  float d = m[3], e = m[4], f = m[5];
  float g = m[6], h = m[7], i = m[8];
  float A = e * i - f * h;
  float B = -(d * i - f * g);
  float C = d * h - e * g;
  float det = a * A + b * B + c * C;
  float id = 1.0f / det;
  o[0] = A * id;            o[1] = -(b * i - c * h) * id; o[2] = (b * f - c * e) * id;
  o[3] = B * id;            o[4] = (a * i - c * g) * id;  o[5] = -(a * f - c * d) * id;
  o[6] = C * id;            o[7] = -(a * h - b * g) * id; o[8] = (a * e - b * d) * id;
}

__device__ inline float wrap_pi(float a) {
  if (a > PI_F) return a - 2.0f * PI_F;
  if (a < -PI_F) return a + 2.0f * PI_F;
  return a;
}

__constant__ float DIM_REF_C[9] = {3.88f, 1.63f, 1.53f,
                                   0.84f, 1.76f, 0.66f,
                                   1.78f, 1.52f, 1.78f};

__global__ __launch_bounds__(768) void rank3_decode_kernel(
    const float* __restrict__ heat,
    const int* __restrict__ counts,
    const unsigned long long* __restrict__ segkey,
    const float* __restrict__ regr,      // [B][8][HWp]
    const float* __restrict__ trans_mat, // [B][3][3]
    const float* __restrict__ K_mat,     // [B][3][3]
    const float* __restrict__ img_size,  // [B][2]
    float* __restrict__ out) {           // [B*50][14]
  const int b = blockIdx.x;
  const int tid = threadIdx.x;
  const int g = tid >> 8;        // plane group 0..2
  const int t = tid & 255;       // lane within group

  __shared__ unsigned long long s_key[NCLS][CAP];   // raw candidates
  __shared__ unsigned long long g_key[NCLS][CAP];   // bucket-grouped
  __shared__ int s_off[NCLS][SEGBLK + 1];
  __shared__ int cnt[NCLS][RBK], suf[NCLS][RBK], cur[NCLS][RBK];
  __shared__ unsigned int fb_hist[1024];
  __shared__ float cls_sc[NCLS * KTOP];
  __shared__ int cls_pi[NCLS * KTOP];
  __shared__ int sel[KTOP];
  __shared__ int s_flag[NCLS], s_M[NCLS], s_fast[NCLS], s_all_fast;
  __shared__ int fb_cnt, fb_B, fb_above, fb_T;

  const int plane = b * NCLS + g;

  if (tid == 0) s_all_fast = 1;
  if (t == 0) { s_flag[g] = 0; s_off[g][0] = 0; }
  __syncthreads();
  if (t < SEGBLK) {
    int n = counts[plane * SEGBLK + t];
    if (n > SEGCAP) { atomicOr(&s_flag[g], 1); n = SEGCAP; }
    s_off[g][t + 1] = n;
  }
  __syncthreads();
  if (t == 0) {
    int acc = 0;
    for (int i = 1; i <= SEGBLK; ++i) { acc += s_off[g][i]; s_off[g][i] = acc; }
    s_M[g] = acc;
    const int fast = (s_flag[g] == 0) && (acc >= KTOP) && (acc <= CAP);
    s_fast[g] = fast;
    if (!fast) s_all_fast = 0;
  }
  __syncthreads();

  if (s_all_fast) {
    // Parallel staging: each group stages its plane's segments (coalesced).
    const unsigned long long* pk = segkey + (size_t)plane * SEGBLK * SEGCAP;
    for (int i = t; i < SEGBLK * SEGCAP; i += 256) {
      const int s = i >> 6;       // / SEGCAP
      const int j = i & (SEGCAP - 1);
      const int o = s_off[g][s];
      const int n = s_off[g][s + 1] - o;
      if (j < n) s_key[g][o + j] = pk[(size_t)s * SEGCAP + j];
    }
  } else {
    // Serial per-plane fallback, all 768 threads, uniform barriers.
    // Exact radix-select rescan (values >= 0); never triggers on this data.
    for (int p = 0; p < NCLS; ++p) {
      if (s_fast[p]) {
        const unsigned long long* pk =
            segkey + (size_t)(b * NCLS + p) * SEGBLK * SEGCAP;
        for (int i = tid; i < SEGBLK * SEGCAP; i += 768) {
          const int s = i >> 6;
          const int j = i & (SEGCAP - 1);
          const int o = s_off[p][s];
          const int n = s_off[p][s + 1] - o;
          if (j < n) s_key[p][o + j] = pk[(size_t)s * SEGCAP + j];
        }
        __syncthreads();
      } else {
        const float* hp = heat + (size_t)(b * NCLS + p) * HWp;
        for (int i = tid; i < 1024; i += 768) fb_hist[i] = 0;
        __syncthreads();
        for_each_peak_plane(hp, tid, 768, [&](unsigned int bits, int idx) {
          unsigned int bkt = bits >> 20; if (bkt > 1023u) bkt = 1023u;
          atomicAdd(&fb_hist[bkt], 1u);
        });
        __syncthreads();
        if (tid == 0) {
          int acc = 0, Bs = -1;
          for (int bkt = 1023; bkt >= 0; --bkt) {
            int cc = (int)fb_hist[bkt];
            if (acc + cc >= KTOP) { Bs = bkt; fb_above = acc; break; }
            acc += cc;
          }
          fb_B = Bs;
          if (Bs < 0) fb_above = acc;
        }
        __syncthreads();
        const int Bs = fb_B;
        unsigned int T;
        if (Bs < 0) {
          T = 0;  // fewer than 50 peaks total: take them all
        } else {
          for (int i = tid; i < 1024; i += 768) fb_hist[i] = 0;
          __syncthreads();
          for_each_peak_plane(hp, tid, 768, [&](unsigned int bits, int idx) {
            unsigned int bkt = bits >> 20; if (bkt > 1023u) bkt = 1023u;
            if ((int)bkt == Bs) atomicAdd(&fb_hist[(bits >> 10) & 1023], 1u);
          });
          __syncthreads();
          if (tid == 0) {
            int acc = fb_above, Ss = 0;
            for (int sb = 1023; sb >= 0; --sb) {
              int cc = (int)fb_hist[sb];
              if (acc + cc >= KTOP) { Ss = sb; break; }
              acc += cc;
            }
            fb_T = (int)(((unsigned int)Bs << 20) | ((unsigned int)Ss << 10));
          }
          __syncthreads();
          T = (unsigned int)fb_T;
        }
        if (tid == 0) fb_cnt = 0;
        __syncthreads();
        for_each_peak_plane(hp, tid, 768, [&](unsigned int bits, int idx) {
          if (bits >= T) {
            int slot = atomicAdd(&fb_cnt, 1);
            if (slot < CAP) s_key[p][slot] = mk_key(bits, idx);
          }
        });
        __syncthreads();
        if (tid == 0) s_M[p] = fb_cnt < CAP ? fb_cnt : CAP;
        __syncthreads();
      }
    }
  }
  __syncthreads();
  const int M = s_M[g];

  // ---- O(M) counting-sort rank per group: (value desc, idx asc) order. ----
  for (int i = t; i < RBK; i += 256) { cnt[g][i] = 0; cur[g][i] = 0; }
  __syncthreads();
  for (int i = t; i < M; i += 256)
    atomicAdd(&cnt[g][bucket_of((unsigned int)(s_key[g][i] >> 32))], 1);
  __syncthreads();
  if (t == 0) {
    int acc = 0;
    for (int bq = RBK - 1; bq >= 0; --bq) { suf[g][bq] = acc; acc += cnt[g][bq]; }
  }
  __syncthreads();
  for (int i = t; i < M; i += 256) {
    const unsigned long long k = s_key[g][i];
    const int bq = bucket_of((unsigned int)(k >> 32));
    const int slot = suf[g][bq] + atomicAdd(&cur[g][bq], 1);
    g_key[g][slot] = k;
  }
  __syncthreads();
  for (int i = t; i < M; i += 256) {
    const unsigned long long k = g_key[g][i];
    const int bq = bucket_of((unsigned int)(k >> 32));
    const int st = suf[g][bq];
    const int nb = cnt[g][bq];
    int rank = st;
    for (int tt = st; tt < st + nb; ++tt) rank += (g_key[g][tt] > k);
    if (rank < KTOP) {
      cls_sc[g * KTOP + rank] = __uint_as_float((unsigned int)(k >> 32));
      cls_pi[g * KTOP + rank] = (int)~((unsigned int)k);
    }
  }
  for (int s2 = M + t; s2 < KTOP; s2 += 256) {
    cls_sc[g * KTOP + s2] = 0.0f;
    cls_pi[g * KTOP + s2] = 0;
  }
  __syncthreads();

  // Batch-level top-50 over 150 scores (tie: lower flattened position wins).
  if (tid < NCLS * KTOP) {
    const float v = cls_sc[tid];
    int rank = 0;
    for (int j = 0; j < NCLS * KTOP; ++j) {
      const float w = cls_sc[j];
      rank += (w > v) || (w == v && j < tid);
    }
    if (rank < KTOP) sel[rank] = tid;
  }
  __syncthreads();

  if (tid < KTOP) {
    const int i = sel[tid];
    const int cls = i / KTOP;
    const float score = cls_sc[i];
    const int ind = cls_pi[i];
    const float ys = (float)(ind / Wd);
    const float xs = (float)(ind - (ind / Wd) * Wd);

    const float* rb = regr + (size_t)b * 8 * HWp + ind;
    const float r0 = rb[0 * HWp], r1 = rb[1 * HWp], r2 = rb[2 * HWp], r3 = rb[3 * HWp];
    const float r4 = rb[4 * HWp], r5 = rb[5 * HWp], r6 = rb[6 * HWp], r7 = rb[7 * HWp];

    float tm[9], km[9], tmi[9], kmi[9];
#pragma unroll
    for (int q = 0; q < 9; ++q) { tm[q] = trans_mat[b * 9 + q]; km[q] = K_mat[b * 9 + q]; }
    inv3(tm, tmi);
    inv3(km, kmi);

    const float px = xs + r1, py = ys + r2;
    const float gx = tmi[0] * px + tmi[1] * py + tmi[2];
    const float gy = tmi[3] * px + tmi[4] * py + tmi[5];
    const float gz = tmi[6] * px + tmi[7] * py + tmi[8];
    const float depth = r0 * 16.32f + 28.01f;
    const float qx = gx * depth, qy = gy * depth, qz = gz * depth;
    const float lx = kmi[0] * qx + kmi[1] * qy + kmi[2] * qz;
    float ly = kmi[3] * qx + kmi[4] * qy + kmi[5] * qz;
    const float lz = kmi[6] * qx + kmi[7] * qy + kmi[8] * qz;

    const float d0 = expf(r3) * DIM_REF_C[cls * 3 + 0];
    const float d1 = expf(r4) * DIM_REF_C[cls * 3 + 1];
    const float d2 = expf(r5) * DIM_REF_C[cls * 3 + 2];
    ly += d1 * 0.5f;

    const float ray = atanf(lx / (lz + 1e-7f));
    float alpha = atanf(r6 / (r7 + 1e-7f));
    alpha += (r7 >= 0.0f) ? -PI_F * 0.5f : PI_F * 0.5f;
    const float roty = wrap_pi(alpha + ray);
    alpha = wrap_pi(alpha);

    const float SX[8] = {-0.5f, 0.5f, 0.5f, 0.5f, 0.5f, -0.5f, -0.5f, -0.5f};
    const float SY[8] = {-1.0f, -1.0f, 0.0f, 0.0f, -1.0f, -1.0f, 0.0f, 0.0f};
    const float SZ[8] = {-0.5f, -0.5f, -0.5f, 0.5f, 0.5f, 0.5f, 0.5f, -0.5f};
    const float cr = cosf(roty), sr = sinf(roty);
    float minx = INFINITY, maxx = -INFINITY, miny = INFINITY, maxy = -INFINITY;
#pragma unroll
    for (int j = 0; j < 8; ++j) {
      const float ax = d0 * SX[j], ay = d1 * SY[j], az = d2 * SZ[j];
      const float cx = cr * ax + sr * az + lx;
      const float cy = ay + ly;
      const float cz = -sr * ax + cr * az + lz;
      const float ppx = km[0] * cx + km[1] * cy + km[2] * cz;
      const float ppy = km[3] * cx + km[4] * cy + km[5] * cz;
      const float ppz = km[6] * cx + km[7] * cy + km[8] * cz;
      const float X = ppx / ppz, Y = ppy / ppz;
      minx = fminf(minx, X); maxx = fmaxf(maxx, X);
      miny = fminf(miny, Y); maxy = fmaxf(maxy, Y);
    }
    const float Wi = img_size[b * 2 + 0], Hi = img_size[b * 2 + 1];
    const float xmin = fminf(fmaxf(minx, 0.0f), Wi);
    const float ymin = fminf(fmaxf(miny, 0.0f), Hi);
    const float xmax = fminf(fmaxf(maxx, 0.0f), Wi);
    const float ymax = fminf(fmaxf(maxy, 0.0f), Hi);

    float* o = out + (size_t)(b * KTOP + tid) * 14;
    if (score > 0.25f) {
      o[0] = (float)cls; o[1] = alpha;
      o[2] = xmin; o[3] = ymin; o[4] = xmax; o[5] = ymax;
      o[6] = d1; o[7] = d2; o[8] = d0;   // dims rolled by -1
      o[9] = lx; o[10] = ly; o[11] = lz;
      o[12] = roty; o[13] = score;
    } else {
#pragma unroll
      for (int q = 0; q < 14; ++q) o[q] = 0.0f;
    }
  }
}

// ---------------------------------------------------------------------------

extern "C" void kernel_launch(void* const* d_in, const int* in_sizes, int n_in,
                              void* d_out, int out_size, void* d_ws, size_t ws_size,
                              hipStream_t stream) {
  const float* heat = (const float*)d_in[0];  // [32,3,192,640]
  const float* regr = (const float*)d_in[1];  // [32,8,192,640]
  const float* tmat = (const float*)d_in[2];  // [32,3,3]
  const float* kmat = (const float*)d_in[3];  // [32,3,3]
  const float* isz = (const float*)d_in[4];   // [32,2]

  // Workspace: counts (NPL*SEGBLK ints) @0, segkey (u64, 8-aligned) @16384.
  char* ws = (char*)d_ws;
  int* counts = (int*)ws;
  unsigned long long* segkey = (unsigned long long*)(ws + 16384);

  scan_kernel<<<NPL * SEGBLK, 256, 0, stream>>>(heat, counts, segkey);
  rank3_decode_kernel<<<NB, 768, 0, stream>>>(heat, counts, segkey,
                                              regr, tmat, kmat, isz,
                                              (float*)d_out);
}